// Round 6
// baseline (344.362 us; speedup 1.0000x reference)
//
#include <hip/hip_runtime.h>
#include <stdint.h>
#include <math.h>

typedef __attribute__((ext_vector_type(8))) short short8;
typedef __attribute__((ext_vector_type(4))) float float4v;

__device__ __forceinline__ uint16_t f2bf(float f){
  union { float f; uint32_t i; } c; c.f = f;
  uint32_t r = c.i + 0x7fffu + ((c.i >> 16) & 1u);   // round-to-nearest-even
  return (uint16_t)(r >> 16);
}
__device__ __forceinline__ uint32_t pack2(float lo, float hi){
  return (uint32_t)f2bf(lo) | ((uint32_t)f2bf(hi) << 16);
}
__device__ __forceinline__ void acc_bf2(uint32_t w, float& x, float& y){
  union { uint32_t i; float f; } a, b;
  a.i = w << 16; b.i = w & 0xffff0000u;
  x += a.f; y += b.f;
}
__device__ __forceinline__ void accum8(uint4 v, float* a){
  acc_bf2(v.x, a[0], a[1]); acc_bf2(v.y, a[2], a[3]);
  acc_bf2(v.z, a[4], a[5]); acc_bf2(v.w, a[6], a[7]);
}

// ---- prep: degree count (global atomics) + fp32->bf16 conversions ----------
// Block-range split: first cntblk blocks count degrees, the rest convert.
// Intra-node edge order is irrelevant for a mean -> no sort needed anywhere.

__global__ __launch_bounds__(256) void prep_kernel(
    const int* __restrict__ ei, int E, int cntblk,
    int* __restrict__ deg,
    const float* __restrict__ x,
    const float* __restrict__ w0, const float* __restrict__ w1,
    const float* __restrict__ w2, const float* __restrict__ w3,
    const float* __restrict__ w4, const float* __restrict__ w5,
    uint16_t* __restrict__ xb, uint16_t* __restrict__ wb, int nx){
  if ((int)blockIdx.x < cntblk){
    int i = blockIdx.x * 256 + threadIdx.x;
    int stride = cntblk * 256;
    for (int e = i; e < E; e += stride)
      atomicAdd(&deg[ei[E + e]], 1);               // coalesced dst reads
  } else {
    int i = (blockIdx.x - cntblk) * 256 + threadIdx.x;
    int stride = (gridDim.x - cntblk) * 256;
    // x fp32 -> bf16 row-major; float4 reads, uint2 (4xbf16) writes
    for (int j = i; j < (nx >> 2); j += stride){
      float4 v = ((const float4*)x)[j];
      uint2 o;
      o.x = pack2(v.x, v.y); o.y = pack2(v.z, v.w);
      ((uint2*)xb)[j] = o;
    }
    const int WSZ = 128 * 128;
    for (int j = i; j < 6 * WSZ; j += stride){
      int t = j >> 14, o = j & (WSZ - 1);
      const float* w = t == 0 ? w0 : t == 1 ? w1 : t == 2 ? w2 : t == 3 ? w3 : t == 4 ? w4 : w5;
      wb[j] = f2bf(w[o]);
    }
  }
}

// ---- scan: one block, 64 nodes/thread, exclusive prefix -> rowptr + cursor -
// deg is padded/zeroed to 65536 so vector loads need no bounds checks.

__global__ __launch_bounds__(1024) void scan_kernel(const int* __restrict__ deg,
                                                    int n,
                                                    int* __restrict__ rowptr,
                                                    int* __restrict__ cursor){
  __shared__ int part[1024];
  int tid = threadIdx.x;
  int4 v[16];
  #pragma unroll
  for (int k = 0; k < 16; ++k) v[k] = ((const int4*)deg)[tid * 16 + k];
  int s = 0;
  #pragma unroll
  for (int k = 0; k < 16; ++k) s += v[k].x + v[k].y + v[k].z + v[k].w;
  part[tid] = s;
  __syncthreads();
  for (int off = 1; off < 1024; off <<= 1){
    int t = (tid >= off) ? part[tid - off] : 0;
    __syncthreads();
    part[tid] += t;
    __syncthreads();
  }
  int run = part[tid] - s;                 // exclusive prefix of this chunk
  int base = tid * 64;
  #pragma unroll
  for (int k = 0; k < 16; ++k){
    int d[4] = { v[k].x, v[k].y, v[k].z, v[k].w };
    #pragma unroll
    for (int q = 0; q < 4; ++q){
      int i = base + k * 4 + q;
      if (i < n){ rowptr[i] = run; cursor[i] = run; }
      run += d[q];
    }
  }
  if (tid == 1023) rowptr[n] = part[1023]; // = E
}

// ---- scatter: direct CSR fill via per-node cursor atomics ------------------

__global__ __launch_bounds__(256) void scatter_kernel(const int* __restrict__ ei,
                                                      int E,
                                                      int* __restrict__ cursor,
                                                      uint32_t* __restrict__ esrc){
  int i = blockIdx.x * 256 + threadIdx.x;
  int stride = gridDim.x * 256;
  for (int e = i; e < E; e += stride){
    int s = ei[e], d = ei[E + e];
    int p = atomicAdd(&cursor[d], 1);
    esrc[p] = (uint32_t)s;
  }
}

// ---- mean aggregation: one wave per NODE, 16 row-gathers in flight ---------
// r0-proven shape: bf16 rows (256B), 16B/lane, 16 lanes/row, 4 edge slots x
// 4-deep unroll. Massive TLP (12.5k blocks, 0 LDS) keeps the random row-
// gather at its ~4.9 TB/s effective fabric ceiling — do not fuse this.

__global__ __launch_bounds__(256) void agg_kernel(const uint16_t* __restrict__ xin,
                                                  const int* __restrict__ rowptr,
                                                  const uint32_t* __restrict__ esrc,
                                                  uint16_t* __restrict__ aggw, int n){
  int node = blockIdx.x * 4 + (threadIdx.x >> 6);
  if (node >= n) return;
  int lane = threadIdx.x & 63;
  int sub = lane >> 4, fq = lane & 15;
  const uint4* xv = (const uint4*)xin;              // row = 16 x uint4
  int beg = rowptr[node], end = rowptr[node + 1];
  float inv = 1.f / fmaxf((float)(end - beg), 1.f);
  float a[8] = {0.f,0.f,0.f,0.f,0.f,0.f,0.f,0.f};
  int e = beg + sub;
  for (; e + 12 < end; e += 16){
    int s0 = esrc[e], s1 = esrc[e + 4], s2 = esrc[e + 8], s3 = esrc[e + 12];
    uint4 v0 = xv[(size_t)s0 * 16 + fq];
    uint4 v1 = xv[(size_t)s1 * 16 + fq];
    uint4 v2 = xv[(size_t)s2 * 16 + fq];
    uint4 v3 = xv[(size_t)s3 * 16 + fq];
    accum8(v0, a); accum8(v1, a); accum8(v2, a); accum8(v3, a);
  }
  for (; e < end; e += 4){
    uint4 v = xv[(size_t)esrc[e] * 16 + fq];
    accum8(v, a);
  }
  #pragma unroll
  for (int i = 0; i < 8; ++i){
    a[i] += __shfl_xor(a[i], 16);
    a[i] += __shfl_xor(a[i], 32);
    a[i] *= inv;
  }
  if (sub == 0){
    uint4 o;
    o.x = pack2(a[0], a[1]); o.y = pack2(a[2], a[3]);
    o.z = pack2(a[4], a[5]); o.w = pack2(a[6], a[7]);
    ((uint4*)aggw)[(size_t)node * 16 + fq] = o;
  }
}

// ---- weight-staged GEMM tiles ----------------------------------------------
// Block = 256 thr (4 waves) owns 64 rows and loops over ALL weight phases
// in-kernel: A-fragments loaded ONCE into registers; each 64-col weight slice
// staged into re-used LDS (34.8 KB -> 4 blocks/CU).
// MFMA 16x16x32 bf16, HW-verified layouts: A[m=lane&15][k=quad*8+j];
// B[k][n=lane&15] from W[col][k]; C/D col=lane&15, row=quad*4+reg.

#define WT_STRIDE 136   // shorts per staged weight row (128 + 8 pad)

__device__ __forceinline__ void stage_weights(const uint16_t* __restrict__ Wl,
                                              const uint16_t* __restrict__ Wr,
                                              int ch, uint16_t* lds_l,
                                              uint16_t* lds_r, int tid){
  const uint4* srcL = (const uint4*)(Wl + (size_t)(ch * 64) * 128);
  const uint4* srcR = (const uint4*)(Wr + (size_t)(ch * 64) * 128);
  #pragma unroll
  for (int i = 0; i < 4; ++i){          // 1024 uint4 per matrix / 256 thr
    int j = tid + i * 256;
    int row = j >> 4, c8 = j & 15;      // 16 uint4 per 128-col row
    uint4 vl = srcL[j], vr = srcR[j];
    *(uint4*)(lds_l + row * WT_STRIDE + c8 * 8) = vl;
    *(uint4*)(lds_r + row * WT_STRIDE + c8 * 8) = vr;
  }
}

// layer 1: x1 = relu(agg@W1l^T + b1 + x@W1r^T), bf16 out. ch looped in-kernel.
__global__ __launch_bounds__(256) void gemm1_kernel(
    const uint16_t* __restrict__ Aagg, const uint16_t* __restrict__ Ax,
    const uint16_t* __restrict__ Wl, const uint16_t* __restrict__ Wr,
    const float* __restrict__ bias, uint16_t* __restrict__ x1b, int n){
  __shared__ uint16_t lds_l[64 * WT_STRIDE], lds_r[64 * WT_STRIDE];
  int tid = threadIdx.x, lane = tid & 63, wid = tid >> 6;
  int m = lane & 15, quad = lane >> 4;
  int r0 = blockIdx.x * 64 + wid * 16;
  int arow = r0 + m; if (arow > n - 1) arow = n - 1;   // clamp tail reads

  short8 a0f[4], a1f[4];
  #pragma unroll
  for (int ks = 0; ks < 4; ++ks){
    a0f[ks] = *(const short8*)(Aagg + (size_t)arow * 128 + ks * 32 + quad * 8);
    a1f[ks] = *(const short8*)(Ax   + (size_t)arow * 128 + ks * 32 + quad * 8);
  }

  for (int ch = 0; ch < 2; ++ch){
    if (ch) __syncthreads();              // prior phase's LDS reads done
    stage_weights(Wl, Wr, ch, lds_l, lds_r, tid);
    __syncthreads();
    float4v acc[4];
    #pragma unroll
    for (int ct = 0; ct < 4; ++ct) acc[ct] = (float4v){0.f, 0.f, 0.f, 0.f};
    #pragma unroll
    for (int ks = 0; ks < 4; ++ks){
      #pragma unroll
      for (int ct = 0; ct < 4; ++ct){
        short8 b0 = *(const short8*)(lds_l + (ct * 16 + m) * WT_STRIDE + ks * 32 + quad * 8);
        acc[ct] = __builtin_amdgcn_mfma_f32_16x16x32_bf16(a0f[ks], b0, acc[ct], 0, 0, 0);
        short8 b1 = *(const short8*)(lds_r + (ct * 16 + m) * WT_STRIDE + ks * 32 + quad * 8);
        acc[ct] = __builtin_amdgcn_mfma_f32_16x16x32_bf16(a1f[ks], b1, acc[ct], 0, 0, 0);
      }
    }
    #pragma unroll
    for (int ct = 0; ct < 4; ++ct){
      int col = ch * 64 + ct * 16 + m;
      float bv = bias[col];
      #pragma unroll
      for (int i = 0; i < 4; ++i){
        int grow = r0 + quad * 4 + i;
        if (grow < n)
          x1b[(size_t)grow * 128 + col] = f2bf(fmaxf(acc[ct][i] + bv, 0.f));
      }
    }
  }
}

// layers 2+3: all 4 (pass, ch) phases looped in-kernel; A read once. fp32 out.
__global__ __launch_bounds__(256) void gemm23_kernel(
    const uint16_t* __restrict__ Aagg, const uint16_t* __restrict__ Ax,
    const uint16_t* __restrict__ W2l, const uint16_t* __restrict__ W2r,
    const float* __restrict__ b2,
    const uint16_t* __restrict__ W3l, const uint16_t* __restrict__ W3r,
    const float* __restrict__ b3,
    float* __restrict__ out, size_t half, int n){
  __shared__ uint16_t lds_l[64 * WT_STRIDE], lds_r[64 * WT_STRIDE];
  int tid = threadIdx.x, lane = tid & 63, wid = tid >> 6;
  int m = lane & 15, quad = lane >> 4;
  int r0 = blockIdx.x * 64 + wid * 16;
  int arow = r0 + m; if (arow > n - 1) arow = n - 1;

  short8 a0f[4], a1f[4];
  #pragma unroll
  for (int ks = 0; ks < 4; ++ks){
    a0f[ks] = *(const short8*)(Aagg + (size_t)arow * 128 + ks * 32 + quad * 8);
    a1f[ks] = *(const short8*)(Ax   + (size_t)arow * 128 + ks * 32 + quad * 8);
  }

  for (int idx = 0; idx < 4; ++idx){
    int pass = idx >> 1, ch = idx & 1;
    if (idx) __syncthreads();
    stage_weights(pass ? W3l : W2l, pass ? W3r : W2r, ch, lds_l, lds_r, tid);
    __syncthreads();
    float4v acc[4];
    #pragma unroll
    for (int ct = 0; ct < 4; ++ct) acc[ct] = (float4v){0.f, 0.f, 0.f, 0.f};
    #pragma unroll
    for (int ks = 0; ks < 4; ++ks){
      #pragma unroll
      for (int ct = 0; ct < 4; ++ct){
        short8 b0 = *(const short8*)(lds_l + (ct * 16 + m) * WT_STRIDE + ks * 32 + quad * 8);
        acc[ct] = __builtin_amdgcn_mfma_f32_16x16x32_bf16(a0f[ks], b0, acc[ct], 0, 0, 0);
        short8 b1 = *(const short8*)(lds_r + (ct * 16 + m) * WT_STRIDE + ks * 32 + quad * 8);
        acc[ct] = __builtin_amdgcn_mfma_f32_16x16x32_bf16(a1f[ks], b1, acc[ct], 0, 0, 0);
      }
    }
    const float* bb = pass ? b3 : b2;
    float* op = out + (pass ? half : 0);
    #pragma unroll
    for (int ct = 0; ct < 4; ++ct){
      int col = ch * 64 + ct * 16 + m;
      float bv = bb[col];
      #pragma unroll
      for (int i = 0; i < 4; ++i){
        int grow = r0 + quad * 4 + i;
        if (grow < n) op[(size_t)grow * 128 + col] = acc[ct][i] + bv;
      }
    }
  }
}

// ---- launcher --------------------------------------------------------------

extern "C" void kernel_launch(void* const* d_in, const int* in_sizes, int n_in,
                              void* d_out, int out_size, void* d_ws, size_t ws_size,
                              hipStream_t stream) {
  const float* x   = (const float*)d_in[0];   // fp32 [N,128]
  const int*   ei  = (const int*)d_in[1];     // int32 [2,E]
  const float* W1l = (const float*)d_in[2];
  const float* b1l = (const float*)d_in[3];
  const float* W1r = (const float*)d_in[4];
  const float* W2l = (const float*)d_in[5];
  const float* b2l = (const float*)d_in[6];
  const float* W2r = (const float*)d_in[7];
  const float* W3l = (const float*)d_in[8];
  const float* b3l = (const float*)d_in[9];
  const float* W3r = (const float*)d_in[10];
  float* out = (float*)d_out;

  const int n = in_sizes[0] / 128;
  const int E = in_sizes[1] / 2;
  const size_t half = (size_t)n * 128;        // elements per output half
  const int WSZ = 128 * 128;
  const int NPAD = 65536;                     // deg padded for vector scan

  size_t off = 0;
  auto carve = [&](size_t bytes) -> void* {
    void* p = (char*)d_ws + off;
    off += (bytes + 255) & ~(size_t)255;
    return p;
  };
  int*      rowptr = (int*)carve((size_t)(n + 1) * 4);
  int*      deg    = (int*)carve((size_t)NPAD * 4);
  int*      cursor = (int*)carve((size_t)NPAD * 4);
  uint32_t* esrc   = (uint32_t*)carve((size_t)E * 4);
  uint16_t* xb     = (uint16_t*)carve(half * 2);            // bf16 x
  uint16_t* wb     = (uint16_t*)carve((size_t)6 * WSZ * 2); // bf16 weights
  uint16_t* x1b    = (uint16_t*)carve(half * 2);            // bf16 x1
  uint16_t* agg    = (uint16_t*)carve(half * 2);            // bf16 agg
  (void)ws_size;  // measured ws_size = 256 MiB >> ~35 MB used

  hipMemsetAsync(deg, 0, (size_t)NPAD * 4, stream);

  const int cntblk = 256, convblk = 768;
  prep_kernel<<<cntblk + convblk, 256, 0, stream>>>(ei, E, cntblk, deg,
                                                    x, W1l, W1r, W2l, W2r, W3l, W3r,
                                                    xb, wb, (int)half);
  scan_kernel<<<1, 1024, 0, stream>>>(deg, n, rowptr, cursor);
  scatter_kernel<<<1024, 256, 0, stream>>>(ei, E, cursor, esrc);

  int ablk = (n + 3) / 4;
  int gblk = (n + 63) / 64;
  const uint16_t *Wb1l = wb, *Wb1r = wb + WSZ, *Wb2l = wb + 2 * WSZ,
                 *Wb2r = wb + 3 * WSZ, *Wb3l = wb + 4 * WSZ, *Wb3r = wb + 5 * WSZ;

  // layer 1
  agg_kernel<<<ablk, 256, 0, stream>>>(xb, rowptr, esrc, agg, n);
  gemm1_kernel<<<gblk, 256, 0, stream>>>(agg, xb, Wb1l, Wb1r, b1l, x1b, n);

  // shared aggregation of x1, then layers 2+3 in one launch
  agg_kernel<<<ablk, 256, 0, stream>>>(x1b, rowptr, esrc, agg, n);
  gemm23_kernel<<<gblk, 256, 0, stream>>>(agg, x1b, Wb2l, Wb2r, b2l,
                                          Wb3l, Wb3r, b3l, out, half, n);
}

// Round 7
// 215.578 us; speedup vs baseline: 1.5974x; 1.5974x over previous
//
#include <hip/hip_runtime.h>
#include <stdint.h>
#include <math.h>

typedef __attribute__((ext_vector_type(8))) short short8;
typedef __attribute__((ext_vector_type(4))) float float4v;

__device__ __forceinline__ uint16_t f2bf(float f){
  union { float f; uint32_t i; } c; c.f = f;
  uint32_t r = c.i + 0x7fffu + ((c.i >> 16) & 1u);   // round-to-nearest-even
  return (uint16_t)(r >> 16);
}
__device__ __forceinline__ uint32_t pack2(float lo, float hi){
  return (uint32_t)f2bf(lo) | ((uint32_t)f2bf(hi) << 16);
}
__device__ __forceinline__ void acc_bf2(uint32_t w, float& x, float& y){
  union { uint32_t i; float f; } a, b;
  a.i = w << 16; b.i = w & 0xffff0000u;
  x += a.f; y += b.f;
}
__device__ __forceinline__ void accum8(uint4 v, float* a){
  acc_bf2(v.x, a[0], a[1]); acc_bf2(v.y, a[2], a[3]);
  acc_bf2(v.z, a[4], a[5]); acc_bf2(v.w, a[6], a[7]);
}

// ---- prep: LDS-staged bucket binning + fp32->bf16 conversions --------------
// Edges are packed src|dst<<16 (n<=65536), bucket = dst>>8. Each 4096-edge
// block sorts its edges by bucket in LDS, reserves contiguous per-bucket
// global ranges, then streams the staged list out in order -> stores land in
// ~21-entry contiguous runs (r6 measured: naive 4-B scatter amplifies 3.2 MB
// of payload into 53 MB of HBM writes; this kills that).

__global__ __launch_bounds__(512) void prep_kernel(
    const int* __restrict__ ei, int E, int NB, int CAP, int p1blk,
    int* __restrict__ fill, uint32_t* __restrict__ bins,
    const float* __restrict__ x,
    const float* __restrict__ w0, const float* __restrict__ w1,
    const float* __restrict__ w2, const float* __restrict__ w3,
    const float* __restrict__ w4, const float* __restrict__ w5,
    uint16_t* __restrict__ xb, uint16_t* __restrict__ wb, int nx){
  if ((int)blockIdx.x < p1blk){
    __shared__ int hist[256], scn[256], cursor[256], gbase[256], excl[256];
    __shared__ uint32_t stage[4096];
    int tid = threadIdx.x;
    if (tid < 256) hist[tid] = 0;
    __syncthreads();
    int e0 = blockIdx.x * 4096;
    int nval = E - e0; if (nval > 4096) nval = 4096;
    uint32_t w[8]; int bk[8];
    #pragma unroll
    for (int k = 0; k < 8; ++k){
      int e = e0 + k * 512 + tid;
      bool ok = e < E;
      int s = ok ? ei[e] : 0;
      int d = ok ? ei[E + e] : 0;
      w[k] = (uint32_t)s | ((uint32_t)d << 16);
      bk[k] = ok ? (d >> 8) : -1;
      if (ok) atomicAdd(&hist[bk[k]], 1);
    }
    __syncthreads();
    if (tid < 256) scn[tid] = hist[tid];
    __syncthreads();
    #pragma unroll
    for (int off = 1; off < 256; off <<= 1){
      int v = 0;
      if (tid < 256 && tid >= off) v = scn[tid - off];
      __syncthreads();
      if (tid < 256) scn[tid] += v;
      __syncthreads();
    }
    if (tid < 256){
      int ex = scn[tid] - hist[tid];
      excl[tid] = ex; cursor[tid] = ex;
      gbase[tid] = (tid < NB && hist[tid] > 0)
                   ? atomicAdd(&fill[tid], hist[tid]) : 0;
    }
    __syncthreads();
    #pragma unroll
    for (int k = 0; k < 8; ++k){
      if (bk[k] >= 0){
        int p = atomicAdd(&cursor[bk[k]], 1);
        stage[p] = w[k];
      }
    }
    __syncthreads();
    for (int i = tid; i < nval; i += 512){
      uint32_t v = stage[i];
      int b = v >> 24;                    // dst>>8 (dst<65536)
      int loc = gbase[b] + (i - excl[b]);
      if (loc < CAP)
        __builtin_nontemporal_store(v, bins + (size_t)b * CAP + loc);
    }
  } else {
    int i = (blockIdx.x - p1blk) * 512 + threadIdx.x;
    int stride = (gridDim.x - p1blk) * 512;
    // x fp32 -> bf16 row-major; float4 reads, uint2 (4xbf16) writes
    for (int j = i; j < (nx >> 2); j += stride){
      float4 v = ((const float4*)x)[j];
      uint2 o;
      o.x = pack2(v.x, v.y); o.y = pack2(v.z, v.w);
      ((uint2*)xb)[j] = o;
    }
    const int WSZ = 128 * 128;
    for (int j = i; j < 6 * WSZ; j += stride){
      int t = j >> 14, o = j & (WSZ - 1);
      const float* w = t == 0 ? w0 : t == 1 ? w1 : t == 2 ? w2 : t == 3 ? w3 : t == 4 ? w4 : w5;
      wb[j] = f2bf(w[o]);
    }
  }
}

// ---- build: per-bucket CSR via LDS reorder + dense coalesced dump ----------
// One WG per 256-node bucket: hist by node, scan, place src into node-sorted
// LDS stage, then esrc[gb+i] = stage[i] fully coalesced (no 4-B scatter).

__global__ __launch_bounds__(512) void build_kernel(const uint32_t* __restrict__ bins,
                                                    const int* __restrict__ fill,
                                                    int CAP, int n,
                                                    int2* __restrict__ rowptr2,
                                                    uint32_t* __restrict__ esrc){
  __shared__ int hist[256], scn[256], cursor[256], excl[256];
  __shared__ uint32_t stage[5120];
  int b = blockIdx.x, tid = threadIdx.x;
  int cnt = fill[b]; if (cnt > CAP) cnt = CAP; if (cnt > 5120) cnt = 5120;
  size_t gb = (size_t)b * CAP;
  if (tid < 256) hist[tid] = 0;
  __syncthreads();
  for (int i = tid; i < cnt; i += 512)
    atomicAdd(&hist[(bins[gb + i] >> 16) & 255], 1);
  __syncthreads();
  if (tid < 256) scn[tid] = hist[tid];
  __syncthreads();
  #pragma unroll
  for (int off = 1; off < 256; off <<= 1){
    int v = 0;
    if (tid < 256 && tid >= off) v = scn[tid - off];
    __syncthreads();
    if (tid < 256) scn[tid] += v;
    __syncthreads();
  }
  if (tid < 256){
    int ex = scn[tid] - hist[tid];
    excl[tid] = ex; cursor[tid] = ex;
    int node = (b << 8) + tid;
    if (node < n) rowptr2[node] = make_int2((int)gb + ex, (int)gb + scn[tid]);
  }
  __syncthreads();
  for (int i = tid; i < cnt; i += 512){
    uint32_t v = bins[gb + i];
    int p = atomicAdd(&cursor[(v >> 16) & 255], 1);
    stage[p] = v & 0xffffu;
  }
  __syncthreads();
  for (int i = tid; i < cnt; i += 512)
    __builtin_nontemporal_store(stage[i], esrc + gb + i);
}

// ---- mean aggregation: one wave per NODE, 16 row-gathers in flight ---------
// r0-proven shape: bf16 rows (256B), 16B/lane, 16 lanes/row, 4 edge slots x
// 4-deep unroll. Massive TLP (12.5k blocks, 0 LDS) keeps the random row-
// gather at its ~4.9 TB/s effective fabric ceiling — do not fuse this.

__global__ __launch_bounds__(256) void agg_kernel(const uint16_t* __restrict__ xin,
                                                  const int2* __restrict__ rowptr2,
                                                  const uint32_t* __restrict__ esrc,
                                                  uint16_t* __restrict__ aggw, int n){
  int node = blockIdx.x * 4 + (threadIdx.x >> 6);
  if (node >= n) return;
  int lane = threadIdx.x & 63;
  int sub = lane >> 4, fq = lane & 15;
  const uint4* xv = (const uint4*)xin;              // row = 16 x uint4
  int2 be = rowptr2[node];
  int beg = be.x, end = be.y;
  float inv = 1.f / fmaxf((float)(end - beg), 1.f);
  float a[8] = {0.f,0.f,0.f,0.f,0.f,0.f,0.f,0.f};
  int e = beg + sub;
  for (; e + 12 < end; e += 16){
    int s0 = esrc[e], s1 = esrc[e + 4], s2 = esrc[e + 8], s3 = esrc[e + 12];
    uint4 v0 = xv[(size_t)s0 * 16 + fq];
    uint4 v1 = xv[(size_t)s1 * 16 + fq];
    uint4 v2 = xv[(size_t)s2 * 16 + fq];
    uint4 v3 = xv[(size_t)s3 * 16 + fq];
    accum8(v0, a); accum8(v1, a); accum8(v2, a); accum8(v3, a);
  }
  for (; e < end; e += 4){
    uint4 v = xv[(size_t)esrc[e] * 16 + fq];
    accum8(v, a);
  }
  #pragma unroll
  for (int i = 0; i < 8; ++i){
    a[i] += __shfl_xor(a[i], 16);
    a[i] += __shfl_xor(a[i], 32);
    a[i] *= inv;
  }
  if (sub == 0){
    uint4 o;
    o.x = pack2(a[0], a[1]); o.y = pack2(a[2], a[3]);
    o.z = pack2(a[4], a[5]); o.w = pack2(a[6], a[7]);
    ((uint4*)aggw)[(size_t)node * 16 + fq] = o;
  }
}

// ---- weight-staged GEMM tiles ----------------------------------------------
// Block = 256 thr (4 waves) owns 64 rows and loops over ALL weight phases
// in-kernel: A-fragments loaded ONCE into registers; each 64-col weight slice
// staged into re-used LDS (34.8 KB -> 4 blocks/CU).
// MFMA 16x16x32 bf16, HW-verified layouts: A[m=lane&15][k=quad*8+j];
// B[k][n=lane&15] from W[col][k]; C/D col=lane&15, row=quad*4+reg.

#define WT_STRIDE 136   // shorts per staged weight row (128 + 8 pad)

__device__ __forceinline__ void stage_weights(const uint16_t* __restrict__ Wl,
                                              const uint16_t* __restrict__ Wr,
                                              int ch, uint16_t* lds_l,
                                              uint16_t* lds_r, int tid){
  const uint4* srcL = (const uint4*)(Wl + (size_t)(ch * 64) * 128);
  const uint4* srcR = (const uint4*)(Wr + (size_t)(ch * 64) * 128);
  #pragma unroll
  for (int i = 0; i < 4; ++i){          // 1024 uint4 per matrix / 256 thr
    int j = tid + i * 256;
    int row = j >> 4, c8 = j & 15;      // 16 uint4 per 128-col row
    uint4 vl = srcL[j], vr = srcR[j];
    *(uint4*)(lds_l + row * WT_STRIDE + c8 * 8) = vl;
    *(uint4*)(lds_r + row * WT_STRIDE + c8 * 8) = vr;
  }
}

// layer 1: x1 = relu(agg@W1l^T + b1 + x@W1r^T), bf16 out. ch looped in-kernel.
__global__ __launch_bounds__(256) void gemm1_kernel(
    const uint16_t* __restrict__ Aagg, const uint16_t* __restrict__ Ax,
    const uint16_t* __restrict__ Wl, const uint16_t* __restrict__ Wr,
    const float* __restrict__ bias, uint16_t* __restrict__ x1b, int n){
  __shared__ uint16_t lds_l[64 * WT_STRIDE], lds_r[64 * WT_STRIDE];
  int tid = threadIdx.x, lane = tid & 63, wid = tid >> 6;
  int m = lane & 15, quad = lane >> 4;
  int r0 = blockIdx.x * 64 + wid * 16;
  int arow = r0 + m; if (arow > n - 1) arow = n - 1;   // clamp tail reads

  short8 a0f[4], a1f[4];
  #pragma unroll
  for (int ks = 0; ks < 4; ++ks){
    a0f[ks] = *(const short8*)(Aagg + (size_t)arow * 128 + ks * 32 + quad * 8);
    a1f[ks] = *(const short8*)(Ax   + (size_t)arow * 128 + ks * 32 + quad * 8);
  }

  for (int ch = 0; ch < 2; ++ch){
    if (ch) __syncthreads();              // prior phase's LDS reads done
    stage_weights(Wl, Wr, ch, lds_l, lds_r, tid);
    __syncthreads();
    float4v acc[4];
    #pragma unroll
    for (int ct = 0; ct < 4; ++ct) acc[ct] = (float4v){0.f, 0.f, 0.f, 0.f};
    #pragma unroll
    for (int ks = 0; ks < 4; ++ks){
      #pragma unroll
      for (int ct = 0; ct < 4; ++ct){
        short8 b0 = *(const short8*)(lds_l + (ct * 16 + m) * WT_STRIDE + ks * 32 + quad * 8);
        acc[ct] = __builtin_amdgcn_mfma_f32_16x16x32_bf16(a0f[ks], b0, acc[ct], 0, 0, 0);
        short8 b1 = *(const short8*)(lds_r + (ct * 16 + m) * WT_STRIDE + ks * 32 + quad * 8);
        acc[ct] = __builtin_amdgcn_mfma_f32_16x16x32_bf16(a1f[ks], b1, acc[ct], 0, 0, 0);
      }
    }
    #pragma unroll
    for (int ct = 0; ct < 4; ++ct){
      int col = ch * 64 + ct * 16 + m;
      float bv = bias[col];
      #pragma unroll
      for (int i = 0; i < 4; ++i){
        int grow = r0 + quad * 4 + i;
        if (grow < n)
          x1b[(size_t)grow * 128 + col] = f2bf(fmaxf(acc[ct][i] + bv, 0.f));
      }
    }
  }
}

// layers 2+3: all 4 (pass, ch) phases looped in-kernel; A read once. fp32 out.
__global__ __launch_bounds__(256) void gemm23_kernel(
    const uint16_t* __restrict__ Aagg, const uint16_t* __restrict__ Ax,
    const uint16_t* __restrict__ W2l, const uint16_t* __restrict__ W2r,
    const float* __restrict__ b2,
    const uint16_t* __restrict__ W3l, const uint16_t* __restrict__ W3r,
    const float* __restrict__ b3,
    float* __restrict__ out, size_t half, int n){
  __shared__ uint16_t lds_l[64 * WT_STRIDE], lds_r[64 * WT_STRIDE];
  int tid = threadIdx.x, lane = tid & 63, wid = tid >> 6;
  int m = lane & 15, quad = lane >> 4;
  int r0 = blockIdx.x * 64 + wid * 16;
  int arow = r0 + m; if (arow > n - 1) arow = n - 1;

  short8 a0f[4], a1f[4];
  #pragma unroll
  for (int ks = 0; ks < 4; ++ks){
    a0f[ks] = *(const short8*)(Aagg + (size_t)arow * 128 + ks * 32 + quad * 8);
    a1f[ks] = *(const short8*)(Ax   + (size_t)arow * 128 + ks * 32 + quad * 8);
  }

  for (int idx = 0; idx < 4; ++idx){
    int pass = idx >> 1, ch = idx & 1;
    if (idx) __syncthreads();
    stage_weights(pass ? W3l : W2l, pass ? W3r : W2r, ch, lds_l, lds_r, tid);
    __syncthreads();
    float4v acc[4];
    #pragma unroll
    for (int ct = 0; ct < 4; ++ct) acc[ct] = (float4v){0.f, 0.f, 0.f, 0.f};
    #pragma unroll
    for (int ks = 0; ks < 4; ++ks){
      #pragma unroll
      for (int ct = 0; ct < 4; ++ct){
        short8 b0 = *(const short8*)(lds_l + (ct * 16 + m) * WT_STRIDE + ks * 32 + quad * 8);
        acc[ct] = __builtin_amdgcn_mfma_f32_16x16x32_bf16(a0f[ks], b0, acc[ct], 0, 0, 0);
        short8 b1 = *(const short8*)(lds_r + (ct * 16 + m) * WT_STRIDE + ks * 32 + quad * 8);
        acc[ct] = __builtin_amdgcn_mfma_f32_16x16x32_bf16(a1f[ks], b1, acc[ct], 0, 0, 0);
      }
    }
    const float* bb = pass ? b3 : b2;
    float* op = out + (pass ? half : 0);
    #pragma unroll
    for (int ct = 0; ct < 4; ++ct){
      int col = ch * 64 + ct * 16 + m;
      float bv = bb[col];
      #pragma unroll
      for (int i = 0; i < 4; ++i){
        int grow = r0 + quad * 4 + i;
        if (grow < n)
          __builtin_nontemporal_store(acc[ct][i] + bv,
                                      op + (size_t)grow * 128 + col);
      }
    }
  }
}

// ---- launcher --------------------------------------------------------------

extern "C" void kernel_launch(void* const* d_in, const int* in_sizes, int n_in,
                              void* d_out, int out_size, void* d_ws, size_t ws_size,
                              hipStream_t stream) {
  const float* x   = (const float*)d_in[0];   // fp32 [N,128]
  const int*   ei  = (const int*)d_in[1];     // int32 [2,E]
  const float* W1l = (const float*)d_in[2];
  const float* b1l = (const float*)d_in[3];
  const float* W1r = (const float*)d_in[4];
  const float* W2l = (const float*)d_in[5];
  const float* b2l = (const float*)d_in[6];
  const float* W2r = (const float*)d_in[7];
  const float* W3l = (const float*)d_in[8];
  const float* b3l = (const float*)d_in[9];
  const float* W3r = (const float*)d_in[10];
  float* out = (float*)d_out;

  const int n = in_sizes[0] / 128;
  const int E = in_sizes[1] / 2;
  const size_t half = (size_t)n * 128;        // elements per output half
  const int WSZ = 128 * 128;

  const int NB = (n + 255) >> 8;              // 256-node buckets (n <= 65536)
  int mean = (E + NB - 1) / NB;
  int CAP = mean + 8 * (int)sqrt((double)mean) + 64;
  CAP = (CAP + 63) & ~63;                     // per-bucket capacity, 8-sigma slack
  if (CAP > 5120) CAP = 5120;                 // build LDS stage bound

  size_t off = 0;
  auto carve = [&](size_t bytes) -> void* {
    void* p = (char*)d_ws + off;
    off += (bytes + 255) & ~(size_t)255;
    return p;
  };
  int2*     rowptr2 = (int2*)carve((size_t)n * 8);
  int*      fill    = (int*)carve((size_t)NB * 4);
  uint32_t* esrc    = (uint32_t*)carve((size_t)NB * CAP * 4);
  uint16_t* xb      = (uint16_t*)carve(half * 2);            // bf16 x
  uint16_t* wb      = (uint16_t*)carve((size_t)6 * WSZ * 2); // bf16 weights
  uint16_t* x1b     = (uint16_t*)carve(half * 2);            // bf16 x1
  uint16_t* agg     = (uint16_t*)carve(half * 2);            // bf16 agg
  uint32_t* bins    = (uint32_t*)carve((size_t)NB * CAP * 4);// packed staging
  (void)ws_size;  // measured ws_size = 256 MiB >> ~35 MB used

  hipMemsetAsync(fill, 0, (size_t)NB * 4, stream);

  int p1blk = (E + 4095) / 4096;              // 4096 edges per binning block
  int cblk  = 512;                            // conversion blocks (grid-stride)
  prep_kernel<<<p1blk + cblk, 512, 0, stream>>>(ei, E, NB, CAP, p1blk, fill, bins,
                                                x, W1l, W1r, W2l, W2r, W3l, W3r,
                                                xb, wb, (int)half);
  build_kernel<<<NB, 512, 0, stream>>>(bins, fill, CAP, n, rowptr2, esrc);

  int ablk = (n + 3) / 4;
  int gblk = (n + 63) / 64;
  const uint16_t *Wb1l = wb, *Wb1r = wb + WSZ, *Wb2l = wb + 2 * WSZ,
                 *Wb2r = wb + 3 * WSZ, *Wb3l = wb + 4 * WSZ, *Wb3r = wb + 5 * WSZ;

  // layer 1
  agg_kernel<<<ablk, 256, 0, stream>>>(xb, rowptr2, esrc, agg, n);
  gemm1_kernel<<<gblk, 256, 0, stream>>>(agg, xb, Wb1l, Wb1r, b1l, x1b, n);

  // shared aggregation of x1, then layers 2+3 in one launch
  agg_kernel<<<ablk, 256, 0, stream>>>(x1b, rowptr2, esrc, agg, n);
  gemm23_kernel<<<gblk, 256, 0, stream>>>(agg, x1b, Wb2l, Wb2r, b2l,
                                          Wb3l, Wb3r, b3l, out, half, n);
}